// Round 1
// baseline (233.783 us; speedup 1.0000x reference)
//
#include <hip/hip_runtime.h>
#include <hip/hip_bf16.h>

// NaN-masked euclidean distances via bf16 MFMA.
// d_ij  = sum_k [ xx_ik*q_jk + p_ik*yy_jk - 2*xc_ik*yc_jk ]
// cnt_ij = sum_k p_ik*q_jk
// out = sqrt(clip(d,0) * D / max(1,cnt)), NaN where cnt==0.

typedef __bf16 bf16_t;
typedef __attribute__((ext_vector_type(8))) __bf16 bf16x8;
typedef __attribute__((ext_vector_type(4))) __bf16 bf16x4;
typedef __attribute__((ext_vector_type(4))) float floatx4;

#define NROWS 4096   // N (X rows)
#define MCOLS 4096   // M (Y rows)
#define DDIM  1024   // K
#define BM 128
#define BN 128
#define BK 32
#define LDK 40       // padded LDS row stride (bf16 elems); 40*2B=80B keeps 16B align, breaks bank aliasing

__global__ __launch_bounds__(256, 2)
void nan_euclid_mfma(const float* __restrict__ X, const float* __restrict__ Y,
                     float* __restrict__ out) {
    __shared__ bf16_t s_xx[BM * LDK];
    __shared__ bf16_t s_p [BM * LDK];
    __shared__ bf16_t s_xc[BM * LDK];
    __shared__ bf16_t s_q [BN * LDK];
    __shared__ bf16_t s_yy[BN * LDK];
    __shared__ bf16_t s_m2[BN * LDK];   // -2*yc

    const int tid  = threadIdx.x;
    const int lane = tid & 63;
    const int wid  = tid >> 6;          // 0..3
    const int quad = lane >> 4;         // 0..3
    const int r16  = lane & 15;
    const int wrow = (wid >> 1) * 64;   // wave row offset in tile
    const int wcol = (wid & 1) * 64;    // wave col offset in tile

    const int blockRow = blockIdx.y * BM;
    const int blockCol = blockIdx.x * BN;

    floatx4 acc_d[4][4];
    floatx4 acc_c[4][4];
    #pragma unroll
    for (int i = 0; i < 4; i++)
        #pragma unroll
        for (int j = 0; j < 4; j++)
            #pragma unroll
            for (int r = 0; r < 4; r++) { acc_d[i][j][r] = 0.f; acc_c[i][j][r] = 0.f; }

    for (int kc = 0; kc < DDIM / BK; kc++) {
        const int kbase = kc * BK;

        // ---- stage A side (X): 128 rows x 32 k, fp32 -> 3 bf16 regions ----
        #pragma unroll
        for (int i = 0; i < 4; i++) {
            int idx = tid + 256 * i;        // float4 index 0..1023
            int row = idx >> 3;             // 0..127
            int c4  = idx & 7;              // 0..7
            const float4 v = *(const float4*)(X + (size_t)(blockRow + row) * DDIM + kbase + c4 * 4);
            bf16x4 vxc, vxx, vp;
            const float xs[4] = {v.x, v.y, v.z, v.w};
            #pragma unroll
            for (int e = 0; e < 4; e++) {
                float x = xs[e];
                bool miss = __builtin_isnan(x);
                float xc = miss ? 0.f : x;
                vxc[e] = (bf16_t)xc;
                vxx[e] = (bf16_t)(xc * xc);
                vp[e]  = miss ? (bf16_t)0.f : (bf16_t)1.f;
            }
            int off = row * LDK + c4 * 4;   // byte offset row*80 + c4*8 -> 8B aligned
            *(bf16x4*)&s_xc[off] = vxc;
            *(bf16x4*)&s_xx[off] = vxx;
            *(bf16x4*)&s_p [off] = vp;
        }

        // ---- stage B side (Y): q, yy, -2*yc ----
        #pragma unroll
        for (int i = 0; i < 4; i++) {
            int idx = tid + 256 * i;
            int row = idx >> 3;
            int c4  = idx & 7;
            const float4 v = *(const float4*)(Y + (size_t)(blockCol + row) * DDIM + kbase + c4 * 4);
            bf16x4 vq, vyy, vm2;
            const float ys[4] = {v.x, v.y, v.z, v.w};
            #pragma unroll
            for (int e = 0; e < 4; e++) {
                float y = ys[e];
                bool miss = __builtin_isnan(y);
                float yc = miss ? 0.f : y;
                vq[e]  = miss ? (bf16_t)0.f : (bf16_t)1.f;
                vyy[e] = (bf16_t)(yc * yc);
                vm2[e] = (bf16_t)(-2.f * yc);
            }
            int off = row * LDK + c4 * 4;
            *(bf16x4*)&s_q [off] = vq;
            *(bf16x4*)&s_yy[off] = vyy;
            *(bf16x4*)&s_m2[off] = vm2;
        }

        __syncthreads();

        // ---- MFMA phase ----
        bf16x8 bq[4], byy[4], bm2[4];
        #pragma unroll
        for (int tn = 0; tn < 4; tn++) {
            int col = wcol + tn * 16 + r16;
            int off = col * LDK + quad * 8;      // elem idx multiple of 8 -> 16B aligned
            bq[tn]  = *(const bf16x8*)&s_q [off];
            byy[tn] = *(const bf16x8*)&s_yy[off];
            bm2[tn] = *(const bf16x8*)&s_m2[off];
        }
        #pragma unroll
        for (int tm = 0; tm < 4; tm++) {
            int rw  = wrow + tm * 16 + r16;
            int off = rw * LDK + quad * 8;
            bf16x8 axx = *(const bf16x8*)&s_xx[off];
            bf16x8 ap  = *(const bf16x8*)&s_p [off];
            bf16x8 axc = *(const bf16x8*)&s_xc[off];
            #pragma unroll
            for (int tn = 0; tn < 4; tn++) {
                acc_d[tm][tn] = __builtin_amdgcn_mfma_f32_16x16x32_bf16(axx, bq[tn],  acc_d[tm][tn], 0, 0, 0);
                acc_d[tm][tn] = __builtin_amdgcn_mfma_f32_16x16x32_bf16(ap,  byy[tn], acc_d[tm][tn], 0, 0, 0);
                acc_d[tm][tn] = __builtin_amdgcn_mfma_f32_16x16x32_bf16(axc, bm2[tn], acc_d[tm][tn], 0, 0, 0);
                acc_c[tm][tn] = __builtin_amdgcn_mfma_f32_16x16x32_bf16(ap,  bq[tn],  acc_c[tm][tn], 0, 0, 0);
            }
        }

        __syncthreads();
    }

    // ---- epilogue: clip, scale, sqrt, store ----
    // C/D layout: col = lane&15, row = quad*4 + reg
    #pragma unroll
    for (int tm = 0; tm < 4; tm++) {
        #pragma unroll
        for (int tn = 0; tn < 4; tn++) {
            int col = blockCol + wcol + tn * 16 + r16;
            #pragma unroll
            for (int r = 0; r < 4; r++) {
                int row = blockRow + wrow + tm * 16 + quad * 4 + r;
                float d = acc_d[tm][tn][r];
                float c = acc_c[tm][tn][r];
                d = fmaxf(d, 0.f);
                float res;
                if (c < 0.5f) {
                    res = __builtin_nanf("");
                } else {
                    res = __builtin_sqrtf(d * (float)DDIM / c);
                }
                out[(size_t)row * MCOLS + col] = res;
            }
        }
    }
}

extern "C" void kernel_launch(void* const* d_in, const int* in_sizes, int n_in,
                              void* d_out, int out_size, void* d_ws, size_t ws_size,
                              hipStream_t stream) {
    const float* X = (const float*)d_in[0];
    const float* Y = (const float*)d_in[1];
    float* out = (float*)d_out;
    dim3 grid(MCOLS / BN, NROWS / BM);   // 32 x 32
    dim3 block(256);
    nan_euclid_mfma<<<grid, block, 0, stream>>>(X, Y, out);
}

// Round 2
// 226.102 us; speedup vs baseline: 1.0340x; 1.0340x over previous
//
#include <hip/hip_runtime.h>
#include <hip/hip_bf16.h>
#include <stdint.h>

// NaN-masked euclidean distances via bf16 MFMA, two-kernel pipeline:
//   prepass: X -> (xx, p, xc) bf16 planes; Y -> (q, yy, -2yc) bf16 planes (in d_ws)
//   main:    d_ij = sum_k [xx*q + p*yy + xc*(-2yc)], cnt_ij = sum_k p*q
//            out = sqrt(clip(d,0)*D/max(1,cnt)), NaN where cnt==0
// Main kernel stages planes into LDS with global_load_lds width=16 using a
// chunk swizzle so fragment reads spread across all 8 LDS superbanks.

typedef __bf16 bf16_t;
typedef __attribute__((ext_vector_type(8))) __bf16 bf16x8;
typedef __attribute__((ext_vector_type(4))) __bf16 bf16x4;
typedef __attribute__((ext_vector_type(4))) float floatx4;

#define NROWS 4096
#define MCOLS 4096
#define DDIM  1024
#define BM 128
#define BN 128
#define BK 32
#define PLANE_ELEMS ((size_t)NROWS * DDIM)      // 4M elems = 8 MB bf16 per plane
#define WS_NEEDED   (6 * PLANE_ELEMS * sizeof(bf16_t))  // 48 MB

// ---------------- prepass: fp32 -> 6 bf16 planes ----------------
__global__ __launch_bounds__(256)
void convert_planes(const float* __restrict__ X, const float* __restrict__ Y,
                    bf16_t* __restrict__ ws) {
    bf16_t* pXX = ws;
    bf16_t* pP  = ws + PLANE_ELEMS;
    bf16_t* pXC = ws + 2 * PLANE_ELEMS;
    bf16_t* pQ  = ws + 3 * PLANE_ELEMS;
    bf16_t* pYY = ws + 4 * PLANE_ELEMS;
    bf16_t* pM2 = ws + 5 * PLANE_ELEMS;

    const size_t nx = PLANE_ELEMS / 4;          // float4 count per input
    size_t id = (size_t)blockIdx.x * 256 + threadIdx.x;

    if (id < nx) {
        const float4 v = ((const float4*)X)[id];
        const float xs[4] = {v.x, v.y, v.z, v.w};
        bf16x4 vxx, vp, vxc;
        #pragma unroll
        for (int e = 0; e < 4; e++) {
            float x = xs[e];
            bool miss = __builtin_isnan(x);
            float xc = miss ? 0.f : x;
            vxc[e] = (bf16_t)xc;
            vxx[e] = (bf16_t)(xc * xc);
            vp[e]  = miss ? (bf16_t)0.f : (bf16_t)1.f;
        }
        ((bf16x4*)pXX)[id] = vxx;
        ((bf16x4*)pP )[id] = vp;
        ((bf16x4*)pXC)[id] = vxc;
    } else {
        size_t j = id - nx;
        const float4 v = ((const float4*)Y)[j];
        const float ys[4] = {v.x, v.y, v.z, v.w};
        bf16x4 vq, vyy, vm2;
        #pragma unroll
        for (int e = 0; e < 4; e++) {
            float y = ys[e];
            bool miss = __builtin_isnan(y);
            float yc = miss ? 0.f : y;
            vq[e]  = miss ? (bf16_t)0.f : (bf16_t)1.f;
            vyy[e] = (bf16_t)(yc * yc);
            vm2[e] = (bf16_t)(-2.f * yc);
        }
        ((bf16x4*)pQ )[j] = vq;
        ((bf16x4*)pYY)[j] = vyy;
        ((bf16x4*)pM2)[j] = vm2;
    }
}

// ---------------- main MFMA kernel ----------------
// LDS: 6 planes of [128 rows x 32 k] bf16 = 8192 B each, 48 KB total.
// Chunk swizzle (16B chunks, 4 per row): chunk16(r,kq) = (r<<2) | (kq ^ ((r>>1)&3))
// Staging inverse: lds chunk C holds (r = C>>2, kq = (C&3) ^ ((r>>1)&3)).
__global__ __launch_bounds__(256, 2)
void nan_euclid_main(const bf16_t* __restrict__ ws, float* __restrict__ out) {
    __shared__ bf16_t lds[6 * BM * BK];         // 49152 B

    const int tid  = threadIdx.x;
    const int lane = tid & 63;
    const int wid  = tid >> 6;                  // 0..3
    const int quad = lane >> 4;                 // 0..3 (16B chunk within 64B row)
    const int r16  = lane & 15;
    const int wrow = (wid >> 1) * 64;
    const int wcol = (wid & 1) * 64;

    const int blockRow = blockIdx.y * BM;
    const int blockCol = blockIdx.x * BN;

    const char* wsb  = (const char*)ws;
    char* ldsb = (char*)lds;

    // staging precompute: 12 global_load_lds per wave per kc
    uint32_t goff[12];                          // byte offsets into ws (k=0)
    uint32_t loff[12];                          // LDS byte offsets (wave-uniform)
    #pragma unroll
    for (int t = 0; t < 12; t++) {
        int gi = wid * 12 + t;                  // 0..47
        int pl = gi >> 3;                       // plane 0..5
        int ii = gi & 7;                        // instruction within plane 0..7
        int chunk = ii * 64 + lane;             // 16B chunk within plane tile
        int r  = chunk >> 2;                    // row 0..127
        int kq = (chunk & 3) ^ ((r >> 1) & 3);  // swizzle inverse
        int rowg = (pl < 3 ? blockRow : blockCol) + r;
        goff[t] = (uint32_t)((pl * PLANE_ELEMS + (size_t)rowg * DDIM + kq * 8) * 2);
        loff[t] = (uint32_t)(pl * 8192 + ii * 1024);  // lane*16 added by HW
    }

    // fragment-read swizzled LDS byte offsets (within a plane)
    int aswz[4], bswz[4];
    #pragma unroll
    for (int tt = 0; tt < 4; tt++) {
        int m = wrow + tt * 16 + r16;
        aswz[tt] = (((m << 2) | (quad ^ ((m >> 1) & 3))) << 4);
        int n = wcol + tt * 16 + r16;
        bswz[tt] = (((n << 2) | (quad ^ ((n >> 1) & 3))) << 4);
    }

    floatx4 acc_d[4][4];
    floatx4 acc_c[4][4];
    #pragma unroll
    for (int i = 0; i < 4; i++)
        #pragma unroll
        for (int j = 0; j < 4; j++)
            #pragma unroll
            for (int r = 0; r < 4; r++) { acc_d[i][j][r] = 0.f; acc_c[i][j][r] = 0.f; }

    for (int kc = 0; kc < DDIM / BK; kc++) {
        // ---- async stage 6 planes into LDS ----
        #pragma unroll
        for (int t = 0; t < 12; t++) {
            __builtin_amdgcn_global_load_lds(
                (const __attribute__((address_space(1))) void*)(wsb + goff[t] + kc * (BK * 2)),
                (__attribute__((address_space(3))) void*)(ldsb + loff[t]),
                16, 0, 0);
        }
        __syncthreads();

        // ---- MFMA phase ----
        bf16x8 bq[4], byy[4], bm2[4];
        #pragma unroll
        for (int tn = 0; tn < 4; tn++) {
            bq[tn]  = *(const bf16x8*)(ldsb + 3 * 8192 + bswz[tn]);
            byy[tn] = *(const bf16x8*)(ldsb + 4 * 8192 + bswz[tn]);
            bm2[tn] = *(const bf16x8*)(ldsb + 5 * 8192 + bswz[tn]);
        }
        #pragma unroll
        for (int tm = 0; tm < 4; tm++) {
            bf16x8 axx = *(const bf16x8*)(ldsb + 0 * 8192 + aswz[tm]);
            bf16x8 ap  = *(const bf16x8*)(ldsb + 1 * 8192 + aswz[tm]);
            bf16x8 axc = *(const bf16x8*)(ldsb + 2 * 8192 + aswz[tm]);
            #pragma unroll
            for (int tn = 0; tn < 4; tn++) {
                acc_d[tm][tn] = __builtin_amdgcn_mfma_f32_16x16x32_bf16(axx, bq[tn],  acc_d[tm][tn], 0, 0, 0);
                acc_d[tm][tn] = __builtin_amdgcn_mfma_f32_16x16x32_bf16(ap,  byy[tn], acc_d[tm][tn], 0, 0, 0);
                acc_d[tm][tn] = __builtin_amdgcn_mfma_f32_16x16x32_bf16(axc, bm2[tn], acc_d[tm][tn], 0, 0, 0);
                acc_c[tm][tn] = __builtin_amdgcn_mfma_f32_16x16x32_bf16(ap,  bq[tn],  acc_c[tm][tn], 0, 0, 0);
            }
        }
        __syncthreads();
    }

    // ---- epilogue: clip, scale, sqrt, store (C/D: col=lane&15, row=quad*4+reg) ----
    #pragma unroll
    for (int tm = 0; tm < 4; tm++) {
        #pragma unroll
        for (int tn = 0; tn < 4; tn++) {
            int col = blockCol + wcol + tn * 16 + r16;
            #pragma unroll
            for (int r = 0; r < 4; r++) {
                int row = blockRow + wrow + tm * 16 + quad * 4 + r;
                float d = acc_d[tm][tn][r];
                float c = acc_c[tm][tn][r];
                d = fmaxf(d, 0.f);
                float res;
                if (c < 0.5f) {
                    res = __builtin_nanf("");
                } else {
                    res = __builtin_sqrtf(d * (float)DDIM / c);
                }
                out[(size_t)row * MCOLS + col] = res;
            }
        }
    }
}

// ---------------- fallback: round-1 fused kernel (if ws too small) ----------------
#define LDK 40
__global__ __launch_bounds__(256, 2)
void nan_euclid_fused(const float* __restrict__ X, const float* __restrict__ Y,
                      float* __restrict__ out) {
    __shared__ bf16_t s_xx[BM * LDK];
    __shared__ bf16_t s_p [BM * LDK];
    __shared__ bf16_t s_xc[BM * LDK];
    __shared__ bf16_t s_q [BN * LDK];
    __shared__ bf16_t s_yy[BN * LDK];
    __shared__ bf16_t s_m2[BN * LDK];

    const int tid  = threadIdx.x;
    const int lane = tid & 63;
    const int wid  = tid >> 6;
    const int quad = lane >> 4;
    const int r16  = lane & 15;
    const int wrow = (wid >> 1) * 64;
    const int wcol = (wid & 1) * 64;

    const int blockRow = blockIdx.y * BM;
    const int blockCol = blockIdx.x * BN;

    floatx4 acc_d[4][4];
    floatx4 acc_c[4][4];
    #pragma unroll
    for (int i = 0; i < 4; i++)
        #pragma unroll
        for (int j = 0; j < 4; j++)
            #pragma unroll
            for (int r = 0; r < 4; r++) { acc_d[i][j][r] = 0.f; acc_c[i][j][r] = 0.f; }

    for (int kc = 0; kc < DDIM / BK; kc++) {
        const int kbase = kc * BK;
        #pragma unroll
        for (int i = 0; i < 4; i++) {
            int idx = tid + 256 * i;
            int row = idx >> 3;
            int c4  = idx & 7;
            const float4 v = *(const float4*)(X + (size_t)(blockRow + row) * DDIM + kbase + c4 * 4);
            bf16x4 vxc, vxx, vp;
            const float xs[4] = {v.x, v.y, v.z, v.w};
            #pragma unroll
            for (int e = 0; e < 4; e++) {
                float x = xs[e];
                bool miss = __builtin_isnan(x);
                float xc = miss ? 0.f : x;
                vxc[e] = (bf16_t)xc;
                vxx[e] = (bf16_t)(xc * xc);
                vp[e]  = miss ? (bf16_t)0.f : (bf16_t)1.f;
            }
            int off = row * LDK + c4 * 4;
            *(bf16x4*)&s_xc[off] = vxc;
            *(bf16x4*)&s_xx[off] = vxx;
            *(bf16x4*)&s_p [off] = vp;
        }
        #pragma unroll
        for (int i = 0; i < 4; i++) {
            int idx = tid + 256 * i;
            int row = idx >> 3;
            int c4  = idx & 7;
            const float4 v = *(const float4*)(Y + (size_t)(blockCol + row) * DDIM + kbase + c4 * 4);
            bf16x4 vq, vyy, vm2;
            const float ys[4] = {v.x, v.y, v.z, v.w};
            #pragma unroll
            for (int e = 0; e < 4; e++) {
                float y = ys[e];
                bool miss = __builtin_isnan(y);
                float yc = miss ? 0.f : y;
                vq[e]  = miss ? (bf16_t)0.f : (bf16_t)1.f;
                vyy[e] = (bf16_t)(yc * yc);
                vm2[e] = (bf16_t)(-2.f * yc);
            }
            int off = row * LDK + c4 * 4;
            *(bf16x4*)&s_q [off] = vq;
            *(bf16x4*)&s_yy[off] = vyy;
            *(bf16x4*)&s_m2[off] = vm2;
        }
        __syncthreads();
        bf16x8 bq[4], byy[4], bm2[4];
        #pragma unroll
        for (int tn = 0; tn < 4; tn++) {
            int off = (wcol + tn * 16 + r16) * LDK + quad * 8;
            bq[tn]  = *(const bf16x8*)&s_q [off];
            byy[tn] = *(const bf16x8*)&s_yy[off];
            bm2[tn] = *(const bf16x8*)&s_m2[off];
        }
        #pragma unroll
        for (int tm = 0; tm < 4; tm++) {
            int off = (wrow + tm * 16 + r16) * LDK + quad * 8;
            bf16x8 axx = *(const bf16x8*)&s_xx[off];
            bf16x8 ap  = *(const bf16x8*)&s_p [off];
            bf16x8 axc = *(const bf16x8*)&s_xc[off];
            #pragma unroll
            for (int tn = 0; tn < 4; tn++) {
                acc_d[tm][tn] = __builtin_amdgcn_mfma_f32_16x16x32_bf16(axx, bq[tn],  acc_d[tm][tn], 0, 0, 0);
                acc_d[tm][tn] = __builtin_amdgcn_mfma_f32_16x16x32_bf16(ap,  byy[tn], acc_d[tm][tn], 0, 0, 0);
                acc_d[tm][tn] = __builtin_amdgcn_mfma_f32_16x16x32_bf16(axc, bm2[tn], acc_d[tm][tn], 0, 0, 0);
                acc_c[tm][tn] = __builtin_amdgcn_mfma_f32_16x16x32_bf16(ap,  bq[tn],  acc_c[tm][tn], 0, 0, 0);
            }
        }
        __syncthreads();
    }
    #pragma unroll
    for (int tm = 0; tm < 4; tm++) {
        #pragma unroll
        for (int tn = 0; tn < 4; tn++) {
            int col = blockCol + wcol + tn * 16 + r16;
            #pragma unroll
            for (int r = 0; r < 4; r++) {
                int row = blockRow + wrow + tm * 16 + quad * 4 + r;
                float d = acc_d[tm][tn][r];
                float c = acc_c[tm][tn][r];
                d = fmaxf(d, 0.f);
                float res;
                if (c < 0.5f) {
                    res = __builtin_nanf("");
                } else {
                    res = __builtin_sqrtf(d * (float)DDIM / c);
                }
                out[(size_t)row * MCOLS + col] = res;
            }
        }
    }
}

extern "C" void kernel_launch(void* const* d_in, const int* in_sizes, int n_in,
                              void* d_out, int out_size, void* d_ws, size_t ws_size,
                              hipStream_t stream) {
    const float* X = (const float*)d_in[0];
    const float* Y = (const float*)d_in[1];
    float* out = (float*)d_out;

    if (ws_size >= WS_NEEDED) {
        bf16_t* ws = (bf16_t*)d_ws;
        const size_t total4 = 2 * PLANE_ELEMS / 4;          // 2M float4 items
        dim3 cgrid((unsigned)((total4 + 255) / 256));
        convert_planes<<<cgrid, 256, 0, stream>>>(X, Y, ws);
        dim3 grid(MCOLS / BN, NROWS / BM);
        nan_euclid_main<<<grid, dim3(256), 0, stream>>>(ws, out);
    } else {
        dim3 grid(MCOLS / BN, NROWS / BM);
        nan_euclid_fused<<<grid, dim3(256), 0, stream>>>(X, Y, out);
    }
}